// Round 1
// baseline (7433.141 us; speedup 1.0000x reference)
//
#include <hip/hip_runtime.h>
#include <math.h>

#define TT 96
#define BB 128
#define DD 800
#define LL 128
#define SSAMP 10

__device__ __forceinline__ float dot4(float4 w, float4 v) {
  return w.x*v.x + w.y*v.y + w.z*v.z + w.w*v.w;
}
__device__ __forceinline__ float sigm(float x) { return 1.f/(1.f + expf(-x)); }
__device__ __forceinline__ unsigned bf16bits(float f) {
  unsigned u = __float_as_uint(f);
  return (u + 0x7fffu + ((u >> 16) & 1u)) >> 16;   // RTNE to bf16
}

// ---------------- prep ----------------
__global__ void prep_misc(const float* __restrict__ b_ih, const float* __restrict__ b_hh,
                          float* __restrict__ b_lstm, double* __restrict__ accum) {
  int t = threadIdx.x;
  if (t < 512) b_lstm[t] = b_ih[t] + b_hh[t];
  if (t == 0) accum[0] = 0.0;
}

// dst[((k>>2)*J + j)*4 + (k&3)] = src[j*rs + k0 + k]  (interleaved-float4 transpose)
__global__ void prep_transpose(const float* __restrict__ src, float* __restrict__ dst,
                               int J, int rs, int k0, int total) {
  int idx = blockIdx.x * 256 + threadIdx.x;
  if (idx >= total) return;
  int J4 = J * 4;
  int k4 = idx / J4;
  int rem = idx - k4 * J4;
  int j = rem >> 2;
  int kk = rem & 3;
  dst[idx] = src[j * rs + k0 + k4 * 4 + kk];
}

// ---------------- phase 0: x_hat = relu(x @ W_px^T + b_px) for all (t,b) ----------------
__global__ __launch_bounds__(256) void xhat_kernel(const float* __restrict__ x,
                                                   const float* __restrict__ Wpx4,
                                                   const float* __restrict__ b_px,
                                                   float* __restrict__ xhat) {
  __shared__ __align__(16) float sx[8][800];
  const int wg = blockIdx.x, tid = threadIdx.x;
  const int p0 = wg * 8;
  for (int r = 0; r < 8; ++r) {
    int p = p0 + r; int t = p >> 7; int b = p & 127;
    const float* row = x + ((size_t)b * TT + t) * 800;
    for (int col = tid; col < 800; col += 256) sx[r][col] = row[col];
  }
  __syncthreads();
  const int j = tid & 127, g = tid >> 7;
  float acc[4];
  const float bj = b_px[j];
  #pragma unroll
  for (int u = 0; u < 4; ++u) acc[u] = bj;
  const float4* W = (const float4*)Wpx4;
  #pragma unroll 2
  for (int k4 = 0; k4 < 200; ++k4) {
    float4 w = W[k4 * 128 + j];
    #pragma unroll
    for (int u = 0; u < 4; ++u) {
      float4 xv = *(const float4*)&sx[g + 2*u][k4 * 4];
      acc[u] += dot4(w, xv);
    }
  }
  #pragma unroll
  for (int u = 0; u < 4; ++u) {
    int p = p0 + g + 2*u;
    xhat[(size_t)p * 128 + j] = fmaxf(acc[u], 0.f);
  }
}

// ---------------- phase 1: sequential scan, one WG per batch chain ----------------
__global__ __launch_bounds__(256) void phase1_kernel(
    const float* __restrict__ eps, const float* __restrict__ xhat_g,
    const float* __restrict__ Wpr4, const float* __restrict__ b_pr,
    const float* __restrict__ Wen4, const float* __restrict__ b_en,
    const float* __restrict__ Wpz4, const float* __restrict__ b_pz,
    const float* __restrict__ Wihx4, const float* __restrict__ Wihz4,
    const float* __restrict__ Whh4, const float* __restrict__ b_lstm,
    float* __restrict__ g_out, float* __restrict__ g_muq, float* __restrict__ g_sgq,
    float* __restrict__ g_mup, float* __restrict__ g_sgp)
{
  extern __shared__ float smem[];
  float* s_out = smem;            // 128
  float* s_h   = smem + 128;      // 128
  float* s_c   = smem + 256;      // 128
  float* s_xh  = smem + 384;      // 128
  float* s_mup = smem + 512;      // 128
  float* s_sgp = smem + 640;      // 128
  float* s_muq = smem + 768;      // 128
  float* s_sgq = smem + 896;      // 128
  float* s_oacc= smem + 1024;     // 128
  float* s_gxh = smem + 1152;     // 512
  float* s_gate= smem + 1664;     // 512
  float* s_z   = smem + 2176;     // 1280
  float* s_zh  = smem + 3456;     // 1280
  float* s_gall= smem + 4736;     // 2560 (5 samples x 512)
  unsigned* s_whh = (unsigned*)(smem + 7296); // 32768 uints = 128KB packed bf16 W_hh

  const int tid = threadIdx.x;
  const int b = blockIdx.x;

  // W_hh -> LDS as packed bf16 pairs (once)
  for (int i = tid; i < 32768; i += 256) {
    float a0 = Whh4[2*i], a1 = Whh4[2*i + 1];
    s_whh[i] = bf16bits(a0) | (bf16bits(a1) << 16);
  }
  if (tid < 128) { s_out[tid] = 0.f; s_h[tid] = 0.f; s_c[tid] = 0.f; }
  __syncthreads();

  for (int t = 0; t < TT; ++t) {
    const size_t pb = (size_t)t * BB + b;
    if (tid < 128) {
      s_xh[tid] = xhat_g[pb * 128 + tid];
      g_out[pb * 128 + tid] = s_out[tid];   // carry-in out for this timestep
      s_oacc[tid] = 0.f;
    }
    __syncthreads();

    // prior: ph = relu(out @ W_pr^T + b_pr)
    {
      const int j = tid;
      float acc = b_pr[j];
      const float4* W = (const float4*)Wpr4;
      #pragma unroll 8
      for (int k4 = 0; k4 < 32; ++k4) {
        float4 w = W[k4 * 256 + j];
        float4 xv = *(const float4*)(s_out + k4 * 4);
        acc += dot4(w, xv);
      }
      float ph = fmaxf(acc, 0.f);
      if (j < 128) {
        s_mup[j] = ph; g_mup[pb * 128 + j] = ph;
      } else {
        float y = expf(ph) + 0.5f;
        float sp = (y > 20.f) ? y : log1pf(expf(y));
        s_sgp[j - 128] = sp; g_sgp[pb * 128 + j - 128] = sp;
      }
    }
    __syncthreads();

    // encoder: eh = relu([out, x_hat] @ W_en^T + b_en)
    {
      const int j = tid;
      float acc = b_en[j];
      const float4* W = (const float4*)Wen4;
      #pragma unroll 8
      for (int k4 = 0; k4 < 32; ++k4) {
        float4 w = W[k4 * 256 + j];
        float4 xv = *(const float4*)(s_out + k4 * 4);
        acc += dot4(w, xv);
      }
      #pragma unroll 8
      for (int k4 = 32; k4 < 64; ++k4) {
        float4 w = W[k4 * 256 + j];
        float4 xv = *(const float4*)(s_xh + (k4 - 32) * 4);
        acc += dot4(w, xv);
      }
      float eh = fmaxf(acc, 0.f);
      if (j < 128) {
        float mq = eh + s_mup[j];
        s_muq[j] = mq; g_muq[pb * 128 + j] = mq;
      } else {
        float sq = expf(eh);
        s_sgq[j - 128] = sq; g_sgq[pb * 128 + j - 128] = sq;
      }
    }
    __syncthreads();

    // z = mu_q + sigma_q * eps
    {
      const float* ep = eps + pb * 1280;
      #pragma unroll
      for (int i = 0; i < 5; ++i) {
        int e = tid + 256 * i;
        int l = e & 127;
        s_z[e] = s_muq[l] + s_sgq[l] * ep[e];
      }
    }
    __syncthreads();

    // z_hat = relu(z @ W_pz^T + b_pz), 10 samples
    {
      const int j = tid & 127;
      const int g5 = (tid >> 7) * 5;
      float acc[5];
      const float bj = b_pz[j];
      #pragma unroll
      for (int u = 0; u < 5; ++u) acc[u] = bj;
      const float4* W = (const float4*)Wpz4;
      #pragma unroll 4
      for (int k4 = 0; k4 < 32; ++k4) {
        float4 w = W[k4 * 128 + j];
        #pragma unroll
        for (int u = 0; u < 5; ++u) {
          float4 zv = *(const float4*)(s_z + (g5 + u) * 128 + k4 * 4);
          acc[u] += dot4(w, zv);
        }
      }
      #pragma unroll
      for (int u = 0; u < 5; ++u) s_zh[(g5 + u) * 128 + j] = fmaxf(acc[u], 0.f);
    }
    // gates_xh = b_lstm + x_hat-half of W_ih (same for all samples)
    {
      const int j = tid;
      float acc = b_lstm[j], acc2 = b_lstm[j + 256];
      const float4* W = (const float4*)Wihx4;
      #pragma unroll 4
      for (int k4 = 0; k4 < 32; ++k4) {
        float4 xv = *(const float4*)(s_xh + k4 * 4);
        float4 w  = W[k4 * 512 + j];
        float4 w2 = W[k4 * 512 + j + 256];
        acc += dot4(w, xv);
        acc2 += dot4(w2, xv);
      }
      s_gxh[j] = acc; s_gxh[j + 256] = acc2;
    }
    __syncthreads();

    for (int half = 0; half < 2; ++half) {
      // gates z-part for samples half*5 .. half*5+4
      {
        const int j = tid;
        const int s0 = half * 5;
        float acc[5], acc2[5];
        const float gx = s_gxh[j], gx2 = s_gxh[j + 256];
        #pragma unroll
        for (int u = 0; u < 5; ++u) { acc[u] = gx; acc2[u] = gx2; }
        const float4* W = (const float4*)Wihz4;
        #pragma unroll 2
        for (int k4 = 0; k4 < 32; ++k4) {
          float4 w  = W[k4 * 512 + j];
          float4 w2 = W[k4 * 512 + j + 256];
          #pragma unroll
          for (int u = 0; u < 5; ++u) {
            float4 zv = *(const float4*)(s_zh + (s0 + u) * 128 + k4 * 4);
            acc[u] += dot4(w, zv);
            acc2[u] += dot4(w2, zv);
          }
        }
        #pragma unroll
        for (int u = 0; u < 5; ++u) {
          s_gall[u * 512 + j] = acc[u];
          s_gall[u * 512 + j + 256] = acc2[u];
        }
      }
      __syncthreads();
      // LSTM recurrence (serial over samples)
      for (int u = 0; u < 5; ++u) {
        const int j = tid, j2 = tid + 256;
        float acc = s_gall[u * 512 + j], acc2 = s_gall[u * 512 + j2];
        #pragma unroll 4
        for (int k4 = 0; k4 < 32; ++k4) {
          float4 hv = *(const float4*)(s_h + k4 * 4);
          unsigned a0 = s_whh[(k4 * 512 + j) * 2 + 0];
          unsigned a1 = s_whh[(k4 * 512 + j) * 2 + 1];
          unsigned c0 = s_whh[(k4 * 512 + j2) * 2 + 0];
          unsigned c1 = s_whh[(k4 * 512 + j2) * 2 + 1];
          acc  += __uint_as_float(a0 << 16) * hv.x + __uint_as_float(a0 & 0xffff0000u) * hv.y
                + __uint_as_float(a1 << 16) * hv.z + __uint_as_float(a1 & 0xffff0000u) * hv.w;
          acc2 += __uint_as_float(c0 << 16) * hv.x + __uint_as_float(c0 & 0xffff0000u) * hv.y
                + __uint_as_float(c1 << 16) * hv.z + __uint_as_float(c1 & 0xffff0000u) * hv.w;
        }
        s_gate[j] = acc; s_gate[j2] = acc2;
        __syncthreads();
        if (tid < 128) {
          const int l = tid;
          float gi = s_gate[l], gf = s_gate[128 + l], gg = s_gate[256 + l], go = s_gate[384 + l];
          float c = sigm(gf) * s_c[l] + sigm(gi) * tanhf(gg);
          float h = sigm(go) * tanhf(c);
          s_c[l] = c; s_h[l] = h; s_oacc[l] += h;
        }
        __syncthreads();
      }
    }
    if (tid < 128) s_out[tid] = s_oacc[tid] * 0.1f;  // mean over S=10
    __syncthreads();
  }
}

// ---------------- phase 2: ELBO terms, fully parallel ----------------
__global__ __launch_bounds__(256) void phase2_kernel(
    const float* __restrict__ x, const float* __restrict__ beta_p,
    const float* __restrict__ eps,
    const float* __restrict__ g_out, const float* __restrict__ g_muq, const float* __restrict__ g_sgq,
    const float* __restrict__ g_mup, const float* __restrict__ g_sgp,
    const float* __restrict__ Wpz4, const float* __restrict__ b_pz,
    const float* __restrict__ Wde4z, const float* __restrict__ Wde4o, const float* __restrict__ b_de,
    double* __restrict__ accum)
{
  __shared__ __align__(16) float s_muq[512], s_sgq[512], s_mup[512], s_sgp[512], s_out[512];
  __shared__ __align__(16) float s_z[5120], s_zh[5120];
  __shared__ float s_wred[4];

  const int tid = threadIdx.x;
  const int p0 = blockIdx.x * 4;       // 4 (t,b) pairs per WG
  const float beta = beta_p[0];
  float acc_loc = 0.f;

  for (int i = tid; i < 512; i += 256) {
    size_t gidx = (size_t)p0 * 128 + i;
    s_muq[i] = g_muq[gidx]; s_sgq[i] = g_sgq[gidx];
    s_mup[i] = g_mup[gidx]; s_sgp[i] = g_sgp[gidx];
    s_out[i] = g_out[gidx];
  }
  __syncthreads();

  // z + KL terms
  for (int pi = 0; pi < 4; ++pi) {
    const float* ep = eps + (size_t)(p0 + pi) * 1280;
    #pragma unroll
    for (int i2 = 0; i2 < 5; ++i2) {
      int e = tid + 256 * i2;
      int l = e & 127;
      float mq = s_muq[pi*128 + l], sq = s_sgq[pi*128 + l];
      float mp = s_mup[pi*128 + l], spv = s_sgp[pi*128 + l];
      float z = mq + sq * ep[e];
      s_z[pi * 1280 + e] = z;
      float aq = (z - mq) / sq;
      float ap = (z - mp) / spv;
      float lq = -0.5f * aq * aq - logf(sq);
      float lp = -0.5f * ap * ap - logf(spv);
      acc_loc -= beta * (lq - lp);
    }
  }
  __syncthreads();

  // z_hat for 40 rows
  {
    const int j = tid & 127;
    const int r0 = (tid >> 7) * 20;
    float acc[20];
    const float bj = b_pz[j];
    #pragma unroll
    for (int u = 0; u < 20; ++u) acc[u] = bj;
    const float4* W = (const float4*)Wpz4;
    for (int k4 = 0; k4 < 32; ++k4) {
      float4 w = W[k4 * 128 + j];
      #pragma unroll
      for (int u = 0; u < 20; ++u) {
        float4 zv = *(const float4*)(s_z + (r0 + u) * 128 + k4 * 4);
        acc[u] += dot4(w, zv);
      }
    }
    #pragma unroll
    for (int u = 0; u < 20; ++u) s_zh[(r0 + u) * 128 + j] = fmaxf(acc[u], 0.f);
  }
  __syncthreads();

  // decoder + Bernoulli log-likelihood; waves split the 13 column-chunks (W_de read once per WG)
  {
    const int wv = tid >> 6, lane = tid & 63;
    const float4* Wz = (const float4*)Wde4z;
    const float4* Wo = (const float4*)Wde4o;
    for (int dc = wv; dc < 13; dc += 4) {
      int d = lane + dc * 64;
      if (d < 800) {
        float acco[4];
        #pragma unroll
        for (int pi = 0; pi < 4; ++pi) acco[pi] = 0.f;
        for (int k4 = 0; k4 < 32; ++k4) {
          float4 w = Wo[k4 * 800 + d];
          #pragma unroll
          for (int pi = 0; pi < 4; ++pi) {
            float4 ov = *(const float4*)(s_out + pi * 128 + k4 * 4);
            acco[pi] += dot4(w, ov);
          }
        }
        float acc[40];
        #pragma unroll
        for (int r = 0; r < 40; ++r) acc[r] = 0.f;
        for (int k4 = 0; k4 < 32; ++k4) {
          float4 w = Wz[k4 * 800 + d];
          #pragma unroll
          for (int r = 0; r < 40; ++r) {
            float4 zv = *(const float4*)(s_zh + r * 128 + k4 * 4);
            acc[r] += dot4(w, zv);
          }
        }
        float bd = b_de[d];
        #pragma unroll
        for (int pi = 0; pi < 4; ++pi) {
          int p = p0 + pi;
          int tt = p >> 7, bb = p & 127;
          float xd = x[((size_t)bb * TT + tt) * 800 + d];
          float suml = 0.f;
          #pragma unroll
          for (int s = 0; s < 10; ++s) {
            float lg = fmaxf(acc[pi * 10 + s] + acco[pi] + bd, 0.f);
            suml += lg;
            acc_loc -= lg + log1pf(expf(-lg));   // softplus(lg), lg >= 0
          }
          acc_loc += xd * suml;
        }
      }
    }
  }

  // block reduction -> one atomic per WG
  float v = acc_loc;
  #pragma unroll
  for (int off = 32; off > 0; off >>= 1) v += __shfl_down(v, off, 64);
  if ((tid & 63) == 0) s_wred[tid >> 6] = v;
  __syncthreads();
  if (tid == 0) {
    double tot = (double)s_wred[0] + (double)s_wred[1] + (double)s_wred[2] + (double)s_wred[3];
    atomicAdd(accum, tot);
  }
}

__global__ void finalize_kernel(const double* __restrict__ accum, float* __restrict__ out) {
  if (threadIdx.x == 0 && blockIdx.x == 0)
    out[0] = (float)(-accum[0] / 122880.0);   // B*T*S
}

// ---------------- host ----------------
extern "C" void kernel_launch(void* const* d_in, const int* in_sizes, int n_in,
                              void* d_out, int out_size, void* d_ws, size_t ws_size,
                              hipStream_t stream) {
  const float* x    = (const float*)d_in[0];
  const float* beta = (const float*)d_in[1];
  const float* eps  = (const float*)d_in[2];
  const float* W_px = (const float*)d_in[3];
  const float* b_px = (const float*)d_in[4];
  const float* W_pz = (const float*)d_in[5];
  const float* b_pz = (const float*)d_in[6];
  const float* W_pr = (const float*)d_in[7];
  const float* b_pr = (const float*)d_in[8];
  const float* W_en = (const float*)d_in[9];
  const float* b_en = (const float*)d_in[10];
  const float* W_de = (const float*)d_in[11];
  const float* b_de = (const float*)d_in[12];
  const float* W_ih = (const float*)d_in[13];
  const float* W_hh = (const float*)d_in[14];
  const float* b_ih = (const float*)d_in[15];
  const float* b_hh = (const float*)d_in[16];
  float* ws = (float*)d_ws;

  // ws offsets (in floats)
  constexpr size_t O_WPX  = 0;
  constexpr size_t O_WPZ  = O_WPX  + 102400;
  constexpr size_t O_WPR  = O_WPZ  + 16384;
  constexpr size_t O_WEN  = O_WPR  + 32768;
  constexpr size_t O_WDEZ = O_WEN  + 65536;
  constexpr size_t O_WDEO = O_WDEZ + 102400;
  constexpr size_t O_WIHX = O_WDEO + 102400;
  constexpr size_t O_WIHZ = O_WIHX + 65536;
  constexpr size_t O_WHH  = O_WIHZ + 65536;
  constexpr size_t O_BL   = O_WHH  + 65536;
  constexpr size_t O_ACC  = O_BL   + 512;      // double, 8B-aligned
  constexpr size_t O_XHAT = O_ACC  + 4;
  constexpr size_t O_OUT  = O_XHAT + 1572864;
  constexpr size_t O_MUQ  = O_OUT  + 1572864;
  constexpr size_t O_SGQ  = O_MUQ  + 1572864;
  constexpr size_t O_MUP  = O_SGQ  + 1572864;
  constexpr size_t O_SGP  = O_MUP  + 1572864;

  prep_misc<<<dim3(1), dim3(512), 0, stream>>>(b_ih, b_hh, ws + O_BL, (double*)(ws + O_ACC));

  auto tp = [&](const float* src, size_t dstOff, int J, int rs, int k0, int Kt) {
    int total = J * Kt;
    prep_transpose<<<dim3((total + 255) / 256), dim3(256), 0, stream>>>(src, ws + dstOff, J, rs, k0, total);
  };
  tp(W_px, O_WPX, 128, 800, 0, 800);
  tp(W_pz, O_WPZ, 128, 128, 0, 128);
  tp(W_pr, O_WPR, 256, 128, 0, 128);
  tp(W_en, O_WEN, 256, 256, 0, 256);
  tp(W_de, O_WDEZ, 800, 256, 0, 128);
  tp(W_de, O_WDEO, 800, 256, 128, 128);
  tp(W_ih, O_WIHX, 512, 256, 0, 128);
  tp(W_ih, O_WIHZ, 512, 256, 128, 128);
  tp(W_hh, O_WHH, 512, 128, 0, 128);

  xhat_kernel<<<dim3(1536), dim3(256), 0, stream>>>(x, ws + O_WPX, b_px, ws + O_XHAT);

  constexpr int P1_LDS = 160256; // 7296 floats + 128KB bf16 W_hh
  hipFuncSetAttribute(reinterpret_cast<const void*>(phase1_kernel),
                      hipFuncAttributeMaxDynamicSharedMemorySize, P1_LDS);
  phase1_kernel<<<dim3(128), dim3(256), P1_LDS, stream>>>(
      eps, ws + O_XHAT, ws + O_WPR, b_pr, ws + O_WEN, b_en, ws + O_WPZ, b_pz,
      ws + O_WIHX, ws + O_WIHZ, ws + O_WHH, ws + O_BL,
      ws + O_OUT, ws + O_MUQ, ws + O_SGQ, ws + O_MUP, ws + O_SGP);

  phase2_kernel<<<dim3(3072), dim3(256), 0, stream>>>(
      x, beta, eps, ws + O_OUT, ws + O_MUQ, ws + O_SGQ, ws + O_MUP, ws + O_SGP,
      ws + O_WPZ, b_pz, ws + O_WDEZ, ws + O_WDEO, b_de, (double*)(ws + O_ACC));

  finalize_kernel<<<dim3(1), dim3(64), 0, stream>>>((const double*)(ws + O_ACC), (float*)d_out);
}

// Round 3
// 5584.377 us; speedup vs baseline: 1.3311x; 1.3311x over previous
//
#include <hip/hip_runtime.h>
#include <math.h>

#define TT 96
#define BB 128
#define DD 800
#define LL 128

typedef _Float16 h2v __attribute__((ext_vector_type(2)));

__device__ __forceinline__ h2v u2h(unsigned u) {
  union { unsigned u; h2v h; } x; x.u = u; return x.h;
}
__device__ __forceinline__ float fdot2(unsigned w, unsigned v, float acc) {
  return __builtin_amdgcn_fdot2(u2h(w), u2h(v), acc, false);
}
__device__ __forceinline__ unsigned packf16(float a, float b) {
  union { _Float16 h[2]; unsigned u; } x;
  x.h[0] = (_Float16)a; x.h[1] = (_Float16)b;
  return x.u;
}
__device__ __forceinline__ float sigm(float x) { return 1.f/(1.f + __expf(-x)); }

__device__ __forceinline__ void dotacc4(uint4 wv, uint4 vv, float4& av) {
  av.x = fdot2(wv.x, vv.x, av.x);
  av.y = fdot2(wv.y, vv.y, av.y);
  av.z = fdot2(wv.z, vv.z, av.z);
  av.w = fdot2(wv.w, vv.w, av.w);
}

// ---------------- prep ----------------
__global__ void prep_misc(const float* __restrict__ b_ih, const float* __restrict__ b_hh,
                          float* __restrict__ b_lstm, double* __restrict__ accum) {
  int t = threadIdx.x;
  if (t < 512) b_lstm[t] = b_ih[t] + b_hh[t];
  if (t == 0) accum[0] = 0.0;
}

// f16 interleaved pack: dst[((k>>3)*J + j)*4 + ((k>>1)&3)] = pack(src[j*rs+k0+k], src[j*rs+k0+k+1])
__global__ void prep_pack_f16(const float* __restrict__ src, unsigned* __restrict__ dst,
                              int J, int rs, int k0, int total) {
  int idx = blockIdx.x * 256 + threadIdx.x;
  if (idx >= total) return;
  int u = idx & 3;
  int t2 = idx >> 2;
  int k8 = t2 / J;
  int j = t2 - k8 * J;
  int k = k8 * 8 + u * 2;
  const float* r = src + (size_t)j * rs + k0 + k;
  dst[idx] = packf16(r[0], r[1]);
}

// fp32 interleaved transpose (for W_px / xhat)
__global__ void prep_transpose(const float* __restrict__ src, float* __restrict__ dst,
                               int J, int rs, int k0, int total) {
  int idx = blockIdx.x * 256 + threadIdx.x;
  if (idx >= total) return;
  int J4 = J * 4;
  int k4 = idx / J4;
  int rem = idx - k4 * J4;
  int j = rem >> 2;
  int kk = rem & 3;
  dst[idx] = src[j * rs + k0 + k4 * 4 + kk];
}

// ---------------- phase 0: x_hat ----------------
__device__ __forceinline__ float dot4(float4 w, float4 v) {
  return w.x*v.x + w.y*v.y + w.z*v.z + w.w*v.w;
}
__global__ __launch_bounds__(256) void xhat_kernel(const float* __restrict__ x,
                                                   const float* __restrict__ Wpx4,
                                                   const float* __restrict__ b_px,
                                                   float* __restrict__ xhat) {
  __shared__ __align__(16) float sx[8][800];
  const int wg = blockIdx.x, tid = threadIdx.x;
  const int p0 = wg * 8;
  for (int r = 0; r < 8; ++r) {
    int p = p0 + r; int t = p >> 7; int b = p & 127;
    const float* row = x + ((size_t)b * TT + t) * 800;
    for (int col = tid; col < 800; col += 256) sx[r][col] = row[col];
  }
  __syncthreads();
  const int j = tid & 127, g = tid >> 7;
  float acc[4];
  const float bj = b_px[j];
  #pragma unroll
  for (int u = 0; u < 4; ++u) acc[u] = bj;
  const float4* W = (const float4*)Wpx4;
  #pragma unroll 2
  for (int k4 = 0; k4 < 200; ++k4) {
    float4 w = W[k4 * 128 + j];
    #pragma unroll
    for (int u = 0; u < 4; ++u) {
      float4 xv = *(const float4*)&sx[g + 2*u][k4 * 4];
      acc[u] += dot4(w, xv);
    }
  }
  #pragma unroll
  for (int u = 0; u < 4; ++u) {
    int p = p0 + g + 2*u;
    xhat[(size_t)p * 128 + j] = fmaxf(acc[u], 0.f);
  }
}

// ---------------- phase 1: sequential scan, one WG (512 thr) per batch chain ----------------
__global__ __launch_bounds__(512) void phase1_kernel(
    const float* __restrict__ eps, const float* __restrict__ xhat_g,
    const uint4* __restrict__ Wpr4, const float* __restrict__ b_pr,
    const uint4* __restrict__ Wen4, const float* __restrict__ b_en,
    const uint4* __restrict__ Wpz4, const float* __restrict__ b_pz,
    const uint4* __restrict__ Wihx4, const uint4* __restrict__ Wihz4,
    const uint4* __restrict__ Whh4, const float* __restrict__ b_lstm,
    float* __restrict__ g_out, float* __restrict__ g_muq, float* __restrict__ g_sgq,
    float* __restrict__ g_mup, float* __restrict__ g_sgp)
{
  __shared__ __align__(16) unsigned s_wpz[8192];   // W_pz f16, LDS-resident
  __shared__ __align__(16) float s_gz[5120];       // gates per sample [10][512]
  __shared__ __align__(16) _Float16 s_z2[1280];
  __shared__ __align__(16) _Float16 s_zh2[1280];
  __shared__ __align__(16) float s_out[128];
  __shared__ __align__(16) float s_ehmu[128];
  __shared__ __align__(16) float s_mup[128];
  __shared__ __align__(16) float s_sgp[128];
  __shared__ __align__(16) float s_sgq[128];
  __shared__ __align__(16) unsigned s_out2[64];
  __shared__ __align__(16) unsigned s_xh2[64];
  __shared__ __align__(16) _Float16 s_h2[128];

  const int tid = threadIdx.x;
  const int b = blockIdx.x;

  // register-resident weight rows (reused 10x per timestep)
  uint4 whh[16], wihz[16];
  #pragma unroll
  for (int k8 = 0; k8 < 16; ++k8) {
    whh[k8]  = Whh4[k8 * 512 + tid];
    wihz[k8] = Wihz4[k8 * 512 + tid];
  }
  for (int i = tid; i < 8192; i += 512) s_wpz[i] = ((const unsigned*)Wpz4)[i];
  if (tid < 128) { s_out[tid] = 0.f; s_h2[tid] = (_Float16)0.f; }
  float c_reg = 0.f;
  const float blst = b_lstm[tid];
  const float bias_pe = (tid < 256) ? b_pr[tid] : b_en[tid - 256];
  const float bpz = b_pz[tid & 127];

  for (int t = 0; t < TT; ++t) {
    const size_t pb = (size_t)t * BB + b;
    const float* epsb = eps + pb * 1280;
    __syncthreads();                       // B0: s_out/s_h2 visible
    float oacc = 0.f;
    if (tid < 128) {
      g_out[pb * 128 + tid] = s_out[tid];
    } else if (tid < 192) {
      int m = tid - 128;
      s_out2[m] = packf16(s_out[2*m], s_out[2*m + 1]);
    } else if (tid < 256) {
      int m = tid - 192;
      s_xh2[m] = packf16(xhat_g[pb * 128 + 2*m], xhat_g[pb * 128 + 2*m + 1]);
    }
    __syncthreads();                       // B1

    // prior (tid<256) / encoder (tid>=256), f16 global weight stream
    {
      float4 a4 = {bias_pe, 0.f, 0.f, 0.f};
      if (tid < 256) {
        #pragma unroll
        for (int k8 = 0; k8 < 16; ++k8) {
          uint4 w = Wpr4[k8 * 256 + tid];
          uint4 o = *(const uint4*)&s_out2[k8 * 4];
          dotacc4(w, o, a4);
        }
        float ph = fmaxf((a4.x + a4.y) + (a4.z + a4.w), 0.f);
        if (tid < 128) { s_mup[tid] = ph; g_mup[pb * 128 + tid] = ph; }
        else {
          float y = expf(ph) + 0.5f;
          float sp = (y > 20.f) ? y : log1pf(expf(y));
          s_sgp[tid - 128] = sp; g_sgp[pb * 128 + tid - 128] = sp;
        }
      } else {
        int j2 = tid - 256;
        #pragma unroll
        for (int k8 = 0; k8 < 16; ++k8) {
          uint4 w = Wen4[k8 * 256 + j2];
          uint4 o = *(const uint4*)&s_out2[k8 * 4];
          dotacc4(w, o, a4);
        }
        #pragma unroll
        for (int k8 = 16; k8 < 32; ++k8) {
          uint4 w = Wen4[k8 * 256 + j2];
          uint4 o = *(const uint4*)&s_xh2[(k8 - 16) * 4];
          dotacc4(w, o, a4);
        }
        float eh = fmaxf((a4.x + a4.y) + (a4.z + a4.w), 0.f);
        if (j2 < 128) s_ehmu[j2] = eh;
        else { float sq = expf(eh); s_sgq[j2 - 128] = sq; g_sgq[pb * 128 + j2 - 128] = sq; }
      }
    }
    __syncthreads();                       // B2

    // z (f16 into LDS) + g_muq
    #pragma unroll
    for (int i = 0; i < 3; ++i) {
      int e = tid + 512 * i;
      if (e < 1280) {
        int l = e & 127;
        float z = (s_ehmu[l] + s_mup[l]) + s_sgq[l] * epsb[e];
        s_z2[e] = (_Float16)z;
      }
    }
    if (tid < 128) g_muq[pb * 128 + tid] = s_ehmu[tid] + s_mup[tid];
    __syncthreads();                       // B3

    // z_hat (W_pz from LDS) — thread covers samples {g, g+4, g+8<10}
    {
      int j = tid & 127, g = tid >> 7;
      float4 a0 = {bpz,0,0,0}, a1 = {bpz,0,0,0}, a2 = {bpz,0,0,0};
      #pragma unroll
      for (int k8 = 0; k8 < 16; ++k8) {
        uint4 w = *(const uint4*)&s_wpz[(k8 * 128 + j) * 4];
        uint4 z0 = *(const uint4*)&s_z2[g * 128 + k8 * 8];
        dotacc4(w, z0, a0);
        uint4 z1 = *(const uint4*)&s_z2[(g + 4) * 128 + k8 * 8];
        dotacc4(w, z1, a1);
        if (g < 2) {
          uint4 z2v = *(const uint4*)&s_z2[(g + 8) * 128 + k8 * 8];
          dotacc4(w, z2v, a2);
        }
      }
      s_zh2[g * 128 + j]       = (_Float16)fmaxf((a0.x+a0.y)+(a0.z+a0.w), 0.f);
      s_zh2[(g + 4) * 128 + j] = (_Float16)fmaxf((a1.x+a1.y)+(a1.z+a1.w), 0.f);
      if (g < 2)
        s_zh2[(g + 8) * 128 + j] = (_Float16)fmaxf((a2.x+a2.y)+(a2.z+a2.w), 0.f);
    }
    // gate-x part into register (W_ihx f16 global stream)
    float gbase;
    {
      float4 a4 = {blst, 0.f, 0.f, 0.f};
      #pragma unroll
      for (int k8 = 0; k8 < 16; ++k8) {
        uint4 w = Wihx4[k8 * 512 + tid];
        uint4 xv = *(const uint4*)&s_xh2[k8 * 4];
        dotacc4(w, xv, a4);
      }
      gbase = (a4.x + a4.y) + (a4.z + a4.w);
    }
    __syncthreads();                       // B4

    // gates-z for all 10 samples (register weights)
    for (int s = 0; s < 10; ++s) {
      float4 a4 = {gbase, 0.f, 0.f, 0.f};
      #pragma unroll
      for (int k8 = 0; k8 < 16; ++k8) {
        uint4 zv = *(const uint4*)&s_zh2[s * 128 + k8 * 8];
        dotacc4(wihz[k8], zv, a4);
      }
      s_gz[s * 512 + tid] = (a4.x + a4.y) + (a4.z + a4.w);
    }
    __syncthreads();                       // B5

    // serial LSTM over 10 samples (register W_hh)
    for (int s = 0; s < 10; ++s) {
      float4 a4 = {s_gz[s * 512 + tid], 0.f, 0.f, 0.f};
      #pragma unroll
      for (int k8 = 0; k8 < 16; ++k8) {
        uint4 hv = *(const uint4*)&s_h2[k8 * 8];
        dotacc4(whh[k8], hv, a4);
      }
      s_gz[s * 512 + tid] = (a4.x + a4.y) + (a4.z + a4.w);
      __syncthreads();
      if (tid < 128) {
        float gi = s_gz[s * 512 + tid],       gf = s_gz[s * 512 + 128 + tid];
        float gg = s_gz[s * 512 + 256 + tid], go = s_gz[s * 512 + 384 + tid];
        c_reg = sigm(gf) * c_reg + sigm(gi) * tanhf(gg);
        float h = sigm(go) * tanhf(c_reg);
        oacc += h;
        s_h2[tid] = (_Float16)h;
      }
      __syncthreads();
    }
    if (tid < 128) s_out[tid] = oacc * 0.1f;
  }
}

// ---------------- phase 2: ELBO terms, fully parallel ----------------
__global__ void phase2_kernel(
    const float* __restrict__ x, const float* __restrict__ beta_p,
    const float* __restrict__ eps,
    const float* __restrict__ g_out, const float* __restrict__ g_muq, const float* __restrict__ g_sgq,
    const float* __restrict__ g_mup, const float* __restrict__ g_sgp,
    const uint4* __restrict__ Wpz4, const float* __restrict__ b_pz,
    const uint4* __restrict__ Wdez4, const uint4* __restrict__ Wdeo4, const float* __restrict__ b_de,
    double* __restrict__ accum)
{
  __shared__ __align__(16) _Float16 s_z2[5120];
  __shared__ __align__(16) _Float16 s_zh2[5120];
  __shared__ __align__(16) unsigned s_out2[256];
  __shared__ __align__(16) float s_muq[512], s_sgq[512], s_mup[512], s_sgp[512];
  __shared__ float s_wred[4];

  const int tid = threadIdx.x;
  const int p0 = blockIdx.x * 4;        // 4 (t,b) pairs -> 40 sample rows
  const float beta = beta_p[0];
  float acc_loc = 0.f;

  for (int i = tid; i < 512; i += 256) {
    size_t gi = (size_t)p0 * 128 + i;
    s_muq[i] = g_muq[gi]; s_sgq[i] = g_sgq[gi];
    s_mup[i] = g_mup[gi]; s_sgp[i] = g_sgp[gi];
  }
  {
    int pair = tid >> 6, m = tid & 63;
    const float* o = g_out + (size_t)p0 * 128 + pair * 128;
    s_out2[tid] = packf16(o[2*m], o[2*m + 1]);
  }
  __syncthreads();

  // KL + z build ((z-muq)/sq == eps exactly)
  {
    int l = tid & 127;
    int ppb = tid >> 7;
    for (int q = 0; q < 2; ++q) {
      int pp = ppb + 2 * q;
      float mq = s_muq[pp*128 + l], sq = s_sgq[pp*128 + l];
      float mp = s_mup[pp*128 + l], spv = s_sgp[pp*128 + l];
      float inv_sp = 1.f / spv;
      float lsq = __logf(sq), lsp = __logf(spv);
      const float* ep = eps + (size_t)(p0 + pp) * 1280 + l;
      float kl = 0.f;
      #pragma unroll
      for (int s = 0; s < 10; ++s) {
        float e = ep[s * 128];
        float z = mq + sq * e;
        s_z2[(pp * 10 + s) * 128 + l] = (_Float16)z;
        float ap = (z - mp) * inv_sp;
        kl += (-0.5f * e * e - lsq) - (-0.5f * ap * ap - lsp);
      }
      acc_loc -= beta * kl;
    }
  }
  __syncthreads();

  // z_hat: 40 rows, W_pz f16 global stream, 20 rows per thread-group
  {
    int j = tid & 127, grp = tid >> 7;
    float acc[20];
    float bj = b_pz[j];
    #pragma unroll
    for (int u = 0; u < 20; ++u) acc[u] = bj;
    for (int k8 = 0; k8 < 16; ++k8) {
      uint4 w = Wpz4[k8 * 128 + j];
      #pragma unroll
      for (int u = 0; u < 20; ++u) {
        uint4 zv = *(const uint4*)&s_z2[(grp * 20 + u) * 128 + k8 * 8];
        acc[u] = fdot2(w.x, zv.x, acc[u]); acc[u] = fdot2(w.y, zv.y, acc[u]);
        acc[u] = fdot2(w.z, zv.z, acc[u]); acc[u] = fdot2(w.w, zv.w, acc[u]);
      }
    }
    #pragma unroll
    for (int u = 0; u < 20; ++u)
      s_zh2[(grp * 20 + u) * 128 + j] = (_Float16)fmaxf(acc[u], 0.f);
  }
  __syncthreads();

  // decoder + Bernoulli; weight rows register-cached (batched global loads)
  for (int dc = 0; dc < 4; ++dc) {
    int d = tid + 256 * dc;
    if (d < 800) {
      uint4 wrow[16];
      #pragma unroll
      for (int k8 = 0; k8 < 16; ++k8) wrow[k8] = Wdeo4[k8 * 800 + d];
      float acco[4] = {0.f, 0.f, 0.f, 0.f};
      #pragma unroll
      for (int k8 = 0; k8 < 16; ++k8) {
        uint4 w = wrow[k8];
        #pragma unroll
        for (int pp = 0; pp < 4; ++pp) {
          uint4 ov = *(const uint4*)&s_out2[pp * 64 + k8 * 4];
          acco[pp] = fdot2(w.x, ov.x, acco[pp]); acco[pp] = fdot2(w.y, ov.y, acco[pp]);
          acco[pp] = fdot2(w.z, ov.z, acco[pp]); acco[pp] = fdot2(w.w, ov.w, acco[pp]);
        }
      }
      #pragma unroll
      for (int k8 = 0; k8 < 16; ++k8) wrow[k8] = Wdez4[k8 * 800 + d];
      float bd = b_de[d];
      for (int pp = 0; pp < 4; ++pp) {
        float acc[10];
        #pragma unroll
        for (int s = 0; s < 10; ++s) acc[s] = 0.f;
        for (int k8 = 0; k8 < 16; ++k8) {
          uint4 w = wrow[k8];
          #pragma unroll
          for (int s = 0; s < 10; ++s) {
            uint4 zv = *(const uint4*)&s_zh2[(pp * 10 + s) * 128 + k8 * 8];
            acc[s] = fdot2(w.x, zv.x, acc[s]); acc[s] = fdot2(w.y, zv.y, acc[s]);
            acc[s] = fdot2(w.z, zv.z, acc[s]); acc[s] = fdot2(w.w, zv.w, acc[s]);
          }
        }
        int p = p0 + pp, tt2 = p >> 7, bb = p & 127;
        float xd = x[((size_t)bb * TT + tt2) * 800 + d];
        float base = acco[pp] + bd;
        #pragma unroll
        for (int s = 0; s < 10; ++s) {
          float lg = fmaxf(acc[s] + base, 0.f);
          acc_loc += xd * lg - lg - __logf(1.f + __expf(-lg));
        }
      }
    }
  }

  // block reduction -> one atomic per WG
  float v = acc_loc;
  #pragma unroll
  for (int off = 32; off > 0; off >>= 1) v += __shfl_down(v, off, 64);
  if ((tid & 63) == 0) s_wred[tid >> 6] = v;
  __syncthreads();
  if (tid == 0) {
    double tot = (double)s_wred[0] + (double)s_wred[1] + (double)s_wred[2] + (double)s_wred[3];
    atomicAdd(accum, tot);
  }
}

__global__ void finalize_kernel(const double* __restrict__ accum, float* __restrict__ out) {
  if (threadIdx.x == 0 && blockIdx.x == 0)
    out[0] = (float)(-accum[0] / 122880.0);   // B*T*S
}

// ---------------- host ----------------
extern "C" void kernel_launch(void* const* d_in, const int* in_sizes, int n_in,
                              void* d_out, int out_size, void* d_ws, size_t ws_size,
                              hipStream_t stream) {
  const float* x    = (const float*)d_in[0];
  const float* beta = (const float*)d_in[1];
  const float* eps  = (const float*)d_in[2];
  const float* W_px = (const float*)d_in[3];
  const float* b_px = (const float*)d_in[4];
  const float* W_pz = (const float*)d_in[5];
  const float* b_pz = (const float*)d_in[6];
  const float* W_pr = (const float*)d_in[7];
  const float* b_pr = (const float*)d_in[8];
  const float* W_en = (const float*)d_in[9];
  const float* b_en = (const float*)d_in[10];
  const float* W_de = (const float*)d_in[11];
  const float* b_de = (const float*)d_in[12];
  const float* W_ih = (const float*)d_in[13];
  const float* W_hh = (const float*)d_in[14];
  const float* b_ih = (const float*)d_in[15];
  const float* b_hh = (const float*)d_in[16];
  float* ws = (float*)d_ws;

  // ws offsets (in 4B units)
  constexpr size_t O_WPX  = 0;                      // 102400 fp32
  constexpr size_t O_WPR  = O_WPX  + 102400;        // 16384 uints
  constexpr size_t O_WEN  = O_WPR  + 16384;         // 32768
  constexpr size_t O_WPZ  = O_WEN  + 32768;         // 8192
  constexpr size_t O_WIHX = O_WPZ  + 8192;          // 32768
  constexpr size_t O_WIHZ = O_WIHX + 32768;         // 32768
  constexpr size_t O_WHH  = O_WIHZ + 32768;         // 32768
  constexpr size_t O_WDEZ = O_WHH  + 32768;         // 51200
  constexpr size_t O_WDEO = O_WDEZ + 51200;         // 51200
  constexpr size_t O_BL   = O_WDEO + 51200;         // 512
  constexpr size_t O_ACC  = O_BL   + 512;           // 2 (double)
  constexpr size_t O_XHAT = O_ACC  + 4;
  constexpr size_t O_OUT  = O_XHAT + 1572864;
  constexpr size_t O_MUQ  = O_OUT  + 1572864;
  constexpr size_t O_SGQ  = O_MUQ  + 1572864;
  constexpr size_t O_MUP  = O_SGQ  + 1572864;
  constexpr size_t O_SGP  = O_MUP  + 1572864;
  (void)O_SGP;

  prep_misc<<<dim3(1), dim3(512), 0, stream>>>(b_ih, b_hh, ws + O_BL, (double*)(ws + O_ACC));

  auto pk = [&](const float* src, size_t off, int J, int rs, int k0, int K) {
    int total = J * (K / 2);
    prep_pack_f16<<<dim3((total + 255) / 256), dim3(256), 0, stream>>>(
        src, (unsigned*)(ws + off), J, rs, k0, total);
  };
  pk(W_pr, O_WPR, 256, 128, 0, 128);
  pk(W_en, O_WEN, 256, 256, 0, 256);
  pk(W_pz, O_WPZ, 128, 128, 0, 128);
  pk(W_ih, O_WIHX, 512, 256, 0, 128);
  pk(W_ih, O_WIHZ, 512, 256, 128, 128);
  pk(W_hh, O_WHH, 512, 128, 0, 128);
  pk(W_de, O_WDEZ, 800, 256, 0, 128);
  pk(W_de, O_WDEO, 800, 256, 128, 128);
  prep_transpose<<<dim3((102400 + 255) / 256), dim3(256), 0, stream>>>(
      W_px, ws + O_WPX, 128, 800, 0, 102400);

  xhat_kernel<<<dim3(1536), dim3(256), 0, stream>>>(x, ws + O_WPX, b_px, ws + O_XHAT);

  phase1_kernel<<<dim3(128), dim3(512), 0, stream>>>(
      eps, ws + O_XHAT,
      (const uint4*)(ws + O_WPR), b_pr, (const uint4*)(ws + O_WEN), b_en,
      (const uint4*)(ws + O_WPZ), b_pz, (const uint4*)(ws + O_WIHX),
      (const uint4*)(ws + O_WIHZ), (const uint4*)(ws + O_WHH), ws + O_BL,
      ws + O_OUT, ws + O_MUQ, ws + O_SGQ, ws + O_MUP, ws + O_SGP);

  phase2_kernel<<<dim3(3072), dim3(256), 0, stream>>>(
      x, beta, eps, ws + O_OUT, ws + O_MUQ, ws + O_SGQ, ws + O_MUP, ws + O_SGP,
      (const uint4*)(ws + O_WPZ), b_pz,
      (const uint4*)(ws + O_WDEZ), (const uint4*)(ws + O_WDEO), b_de,
      (double*)(ws + O_ACC));

  finalize_kernel<<<dim3(1), dim3(64), 0, stream>>>((const double*)(ws + O_ACC), (float*)d_out);
}